// Round 10
// baseline (2785.856 us; speedup 1.0000x reference)
//
#include <hip/hip_runtime.h>

#define SCALE_EPS 1e-5f

typedef int v4i __attribute__((ext_vector_type(4)));
typedef int v16i __attribute__((ext_vector_type(16)));

static __device__ __forceinline__ void gll16(const void* g, void* l) {
  __builtin_amdgcn_global_load_lds(
      (const __attribute__((address_space(1))) unsigned int*)g,
      (__attribute__((address_space(3))) unsigned int*)l,
      16, 0, 0);
}

// Nibble-pair packed operand format (both A and B), biased u = q+8:
//   packed byte e of a 32x32 k-pair fragment: u[k] | u[k+32]<<4
//   fragment lane l = kh*32 + (row_or_col % 32); ds_read_b128 yields BOTH
//   ks=0 (lo nibbles) and ks=1 (hi nibbles) v4i MFMA operands.
// A tile: xq + (mt*64+kc)*8192, off = rb*1024 + lane*16   (rb = row%256/32)
// B tile: wq + (nt*64+kc)*8192, off = cf*1024 + lane*16   (cf = col%256/32)
// Bias removal: C = raw - 8*(sa_signed[t] + swU_biased[o])  (exact).

// ---------------------------------------------------------------------------
// Weight unpack: packed int32 [4096][2048] -> biased nibble-pair tiles.
// ---------------------------------------------------------------------------
__global__ __launch_bounds__(256) void unpack_w(const int* __restrict__ wp,
                                                char* __restrict__ wq) {
  const int kc = blockIdx.x;   // 0..63
  const int nt2 = blockIdx.y;  // 0..15 (256-col tiles)
  const int tid = threadIdx.x;
  char* tile = wq + ((size_t)nt2 * 64 + kc) * 8192;
#pragma unroll
  for (int it = 0; it < 8; ++it) {
    int idx = it * 256 + tid;      // 0..2047
    int c = idx >> 3;              // col in tile 0..255
    int rem = idx & 7;
    int kh = rem >> 2, q = rem & 3;
    const int* src = wp + (size_t)(nt2 * 256 + c) * 2048 + kc * 32 + kh * 8 + q * 2;
    int i0 = src[0], i1 = src[1], j0 = src[16], j1 = src[17];
    unsigned dw = ((unsigned)i0 & 15) | (((unsigned)j0 & 15) << 4) |
                  ((((unsigned)i0 >> 4) & 15) << 8) | ((((unsigned)j0 >> 4) & 15) << 12) |
                  (((unsigned)i1 & 15) << 16) | (((unsigned)j1 & 15) << 20) |
                  ((((unsigned)i1 >> 4) & 15) << 24) | ((((unsigned)j1 >> 4) & 15) << 28);
    dw ^= 0x88888888u;  // raw nibble v -> v^8 = q+8 (biased)
    *(unsigned*)(tile + (c >> 5) * 1024 + (kh * 32 + (c & 31)) * 16 + q * 4) = dw;
  }
}

// ---------------------------------------------------------------------------
// Per-out-feature BIASED nibble sum: swU[o] = sum_k (q_w + 8).
// ---------------------------------------------------------------------------
__global__ __launch_bounds__(256) void sum_w(const int* __restrict__ wp,
                                             int* __restrict__ sw) {
  __shared__ int ls[4];
  const int row = blockIdx.x;
  const int tid = threadIdx.x;
  const v4i* src = (const v4i*)(wp + (size_t)row * 2048 + tid * 8);
  v4i m0 = src[0], m1 = src[1];
  int s = 0;
#pragma unroll
  for (int j = 0; j < 4; ++j) {
    int a = (j == 0) ? m0.x : (j == 1) ? m0.y : (j == 2) ? m0.z : m0.w;
    int b = (j == 0) ? m1.x : (j == 1) ? m1.y : (j == 2) ? m1.z : m1.w;
    s += ((a & 15) ^ 8) + (((a >> 4) & 15) ^ 8) + ((b & 15) ^ 8) + (((b >> 4) & 15) ^ 8);
  }
#pragma unroll
  for (int d = 1; d < 64; d <<= 1) s += __shfl_xor(s, d, 64);
  if ((tid & 63) == 0) ls[tid >> 6] = s;
  __syncthreads();
  if (tid == 0) sw[row] = ls[0] + ls[1] + ls[2] + ls[3];
}

// ---------------------------------------------------------------------------
// Activation quant: per-row absmax scale, q = clip(rint(x/scale),-8,7),
// nibble-pair packed tiles (u = q+8) + per-token SIGNED sum sa[t].
// ---------------------------------------------------------------------------
__global__ __launch_bounds__(256) void quant_x(const float* __restrict__ x,
                                               char* __restrict__ xq,
                                               float* __restrict__ xs,
                                               int* __restrict__ sa) {
  __shared__ float lmax[4][4];
  __shared__ int lsum[4][4];
  const int tid = threadIdx.x;
  const int w = tid >> 6;        // wave -> 16 kc chunk
  const int l = tid & 63;
  const int t0 = blockIdx.x * 4;
  const int row = l >> 4;
  const int t = t0 + row;
  const int sub = l & 15;
  const int kcl = sub >> 3;      // which of 2 kc per s
  const int kh = (sub >> 2) & 1;
  const int j = sub & 3;

  float4 va[8], vb[8];
  float m = 0.0f;
#pragma unroll
  for (int s = 0; s < 8; ++s) {
    int kc = w * 16 + s * 2 + kcl;
    const float* p = x + (size_t)t * 4096 + kc * 64 + kh * 16 + j * 4;
    va[s] = *(const float4*)(p);
    vb[s] = *(const float4*)(p + 32);
    m = fmaxf(m, fmaxf(fmaxf(fabsf(va[s].x), fabsf(va[s].y)),
                       fmaxf(fabsf(va[s].z), fabsf(va[s].w))));
    m = fmaxf(m, fmaxf(fmaxf(fabsf(vb[s].x), fabsf(vb[s].y)),
                       fmaxf(fabsf(vb[s].z), fabsf(vb[s].w))));
  }
#pragma unroll
  for (int d = 1; d < 16; d <<= 1) m = fmaxf(m, __shfl_xor(m, d, 64));
  if (sub == 0) lmax[w][row] = m;
  __syncthreads();
  float rm = fmaxf(fmaxf(lmax[0][row], lmax[1][row]),
                   fmaxf(lmax[2][row], lmax[3][row]));
  float scale = fmaxf(rm / 7.0f, SCALE_EPS);
  if (w == 0 && sub == 0) xs[t] = scale;

  char* dst0 = xq + (size_t)(t >> 8) * 524288 + ((t & 255) >> 5) * 1024 +
               (kh * 32 + (t & 31)) * 16 + j * 4;

  int isum = 0;
#pragma unroll
  for (int s = 0; s < 8; ++s) {
    int kc = w * 16 + s * 2 + kcl;
    int q0 = (int)fminf(fmaxf(rintf(va[s].x / scale), -8.0f), 7.0f);
    int q1 = (int)fminf(fmaxf(rintf(va[s].y / scale), -8.0f), 7.0f);
    int q2 = (int)fminf(fmaxf(rintf(va[s].z / scale), -8.0f), 7.0f);
    int q3 = (int)fminf(fmaxf(rintf(va[s].w / scale), -8.0f), 7.0f);
    int q4 = (int)fminf(fmaxf(rintf(vb[s].x / scale), -8.0f), 7.0f);
    int q5 = (int)fminf(fmaxf(rintf(vb[s].y / scale), -8.0f), 7.0f);
    int q6 = (int)fminf(fmaxf(rintf(vb[s].z / scale), -8.0f), 7.0f);
    int q7 = (int)fminf(fmaxf(rintf(vb[s].w / scale), -8.0f), 7.0f);
    isum += q0 + q1 + q2 + q3 + q4 + q5 + q6 + q7;
    unsigned dw = (unsigned)((q0 + 8) | ((q4 + 8) << 4)) |
                  ((unsigned)((q1 + 8) | ((q5 + 8) << 4)) << 8) |
                  ((unsigned)((q2 + 8) | ((q6 + 8) << 4)) << 16) |
                  ((unsigned)((q3 + 8) | ((q7 + 8) << 4)) << 24);
    *(unsigned*)(dst0 + (size_t)kc * 8192) = dw;
  }
#pragma unroll
  for (int dd = 1; dd < 16; dd <<= 1) isum += __shfl_xor(isum, dd, 64);
  if (sub == 0) lsum[w][row] = isum;
  __syncthreads();
  if (w == 0 && sub == 0)
    sa[t] = lsum[0][row] + lsum[1][row] + lsum[2][row] + lsum[3][row];
}

// ---------------------------------------------------------------------------
// Packed-nibble GEMM, 256x256 tile, 8 waves (2Mx4N), BK=64, mfma 32x32x32 i8.
// R9: barrier moved to tile START (vmcnt(2) certifies slot kt+1 there); the
// 6 ds_reads and 12 half-unpacks for tile kt+1 are SPREAD across the 4 MFMA
// clusters of tile kt, each placed right after the last use of the register
// it overwrites (lo/hi halves split). sched_barrier(0) pins phase boundaries.
// Unpack is pure splat-vector ops (p & 0x0f0f0f0f, (p>>4) & 0x0f0f0f0f):
// 12 VALU/pair, no construction moves -> ~72 VALU/wave/tile, hidden under
// the 4x146-cyc MFMA clusters. Epilogue: C = raw - 8*(sa + swU)  (exact).
// ---------------------------------------------------------------------------
__global__ __launch_bounds__(512, 2) void gemm_i8(const char* __restrict__ xq,
                                                  const char* __restrict__ wq,
                                                  const float* __restrict__ xs,
                                                  const int* __restrict__ sa,
                                                  const int* __restrict__ sw,
                                                  const float* __restrict__ wsc,
                                                  float* __restrict__ out) {
  __shared__ char lds[4][16384];
  const int tid = threadIdx.x;
  const int wid = tid >> 6;
  const int lane = tid & 63;
  const int wm = wid >> 2;         // 0..1 : M half (128 rows)
  const int wn = wid & 3;          // 0..3 : N quarter (64 cols)

  const int bid = blockIdx.x;
  const int wg = (bid & 7) * 64 + (bid >> 3);
  const int by = wg >> 4;          // 0..31
  const int bx = wg & 15;          // 0..15

  const int toff = tid * 16;       // 0..8191
  const char* aSrc = xq + (size_t)by * 524288;
  const char* bSrc = wq + (size_t)bx * 524288;
  const int laoff = lane * 16;

  v16i acc[4][2] = {};             // acc[rb][nf]
  v4i pA0, pA1, pA2, pA3, pB0, pB1;            // packed next-tile
  v4i a00, a01, a10, a11, a20, a21, a30, a31;  // unpacked A [rb][ks]
  v4i b00, b01, b10, b11;                      // unpacked B [nf][ks]
  const v4i M4 = (v4i)(0x0f0f0f0f);

#define STAGE2(kt)                                             \
  do {                                                         \
    char* d_ = lds[(kt) & 3] + toff;                           \
    gll16(aSrc + (size_t)(kt) * 8192 + toff, d_);              \
    gll16(bSrc + (size_t)(kt) * 8192 + toff, d_ + 8192);       \
  } while (0)

  // 4 mfma: rows {rb, rb+1} x col-frags {0,1}
#define CL(rb, xx, yy, bA, bB)                                                 \
  do {                                                                         \
    __builtin_amdgcn_s_setprio(1);                                             \
    acc[rb][0] = __builtin_amdgcn_mfma_i32_32x32x32_i8(xx, bA, acc[rb][0], 0, 0, 0);   \
    acc[rb][1] = __builtin_amdgcn_mfma_i32_32x32x32_i8(xx, bB, acc[rb][1], 0, 0, 0);   \
    acc[rb + 1][0] = __builtin_amdgcn_mfma_i32_32x32x32_i8(yy, bA, acc[rb + 1][0], 0, 0, 0); \
    acc[rb + 1][1] = __builtin_amdgcn_mfma_i32_32x32x32_i8(yy, bB, acc[rb + 1][1], 0, 0, 0); \
    __builtin_amdgcn_s_setprio(0);                                             \
  } while (0)

#define SB __builtin_amdgcn_sched_barrier(0)

#define TILE(kt, do_stage, do_next, vm)                                      \
  do {                                                                       \
    if ((vm) == 2) asm volatile("s_waitcnt vmcnt(2)" ::: "memory");          \
    else if ((vm) == 0) asm volatile("s_waitcnt vmcnt(0)" ::: "memory");     \
    __builtin_amdgcn_s_barrier();                                            \
    SB;                                                                      \
    const char* An_ = lds[((kt) + 1) & 3] + wm * 4096 + laoff;               \
    const char* Bn_ = lds[((kt) + 1) & 3] + 8192 + wn * 2048 + laoff;        \
    if (do_stage) STAGE2((kt) + 3);                                          \
    if (do_next) {                                                           \
      pA0 = *(const v4i*)(An_);                                              \
      pA1 = *(const v4i*)(An_ + 1024);                                       \
      pB0 = *(const v4i*)(Bn_);                                              \
    }                                                                        \
    CL(0, a00, a10, b00, b10);     /* ks0 rb0,rb1 */                         \
    SB;                                                                      \
    if (do_next) {                                                           \
      pA2 = *(const v4i*)(An_ + 2048);                                       \
      pA3 = *(const v4i*)(An_ + 3072);                                       \
      pB1 = *(const v4i*)(Bn_ + 1024);                                       \
    }                                                                        \
    CL(2, a20, a30, b00, b10);     /* ks0 rb2,rb3; last use of ks0 set */    \
    SB;                                                                      \
    if (do_next) {                 /* refill dead ks0 regs (lo nibbles) */   \
      a00 = pA0 & M4; a10 = pA1 & M4; b00 = pB0 & M4;                        \
    }                                                                        \
    CL(0, a01, a11, b01, b11);     /* ks1 rb0,rb1; last use a01,a11 */       \
    SB;                                                                      \
    if (do_next) {                                                           \
      a20 = pA2 & M4; a30 = pA3 & M4; b10 = pB1 & M4;                        \
      a01 = (pA0 >> 4) & M4; a11 = (pA1 >> 4) & M4;                          \
    }                                                                        \
    CL(2, a21, a31, b01, b11);     /* ks1 rb2,rb3; everything dead after */  \
    SB;                                                                      \
    if (do_next) {                                                           \
      a21 = (pA2 >> 4) & M4; a31 = (pA3 >> 4) & M4;                          \
      b01 = (pB0 >> 4) & M4; b11 = (pB1 >> 4) & M4;                          \
    }                                                                        \
  } while (0)

  // prologue: stage tiles 0,1,2; certify slot 0; read+unpack slot-0 operands
  STAGE2(0); STAGE2(1); STAGE2(2);
  asm volatile("s_waitcnt vmcnt(4)" ::: "memory");
  __builtin_amdgcn_s_barrier();
  SB;
  {
    const char* A0_ = lds[0] + wm * 4096 + laoff;
    const char* B0_ = lds[0] + 8192 + wn * 2048 + laoff;
    pA0 = *(const v4i*)(A0_);
    pA1 = *(const v4i*)(A0_ + 1024);
    pA2 = *(const v4i*)(A0_ + 2048);
    pA3 = *(const v4i*)(A0_ + 3072);
    pB0 = *(const v4i*)(B0_);
    pB1 = *(const v4i*)(B0_ + 1024);
    a00 = pA0 & M4; a01 = (pA0 >> 4) & M4;
    a10 = pA1 & M4; a11 = (pA1 >> 4) & M4;
    a20 = pA2 & M4; a21 = (pA2 >> 4) & M4;
    a30 = pA3 & M4; a31 = (pA3 >> 4) & M4;
    b00 = pB0 & M4; b01 = (pB0 >> 4) & M4;
    b10 = pB1 & M4; b11 = (pB1 >> 4) & M4;
  }

  for (int kt = 0; kt < 61; ++kt) TILE(kt, 1, 1, 2);  // tile 60 stages slot 63
  TILE(61, 0, 1, 2);
  TILE(62, 0, 1, 0);
  TILE(63, 0, 0, -1);

#undef TILE
#undef SB
#undef CL
#undef STAGE2

  // epilogue: C/D 32x32: col = lane&31, row = (reg&3)+8*(reg>>2)+4*(lane>>5)
  const int colb = bx * 256 + wn * 64 + (lane & 31);
  int sw0 = sw[colb];
  int sw1 = sw[colb + 32];
  float wv0 = wsc[colb];
  float wv1 = wsc[colb + 32];
  const int rw = by * 256 + wm * 128 + ((lane >> 5) << 2);
#pragma unroll
  for (int rb = 0; rb < 4; ++rb) {
#pragma unroll
    for (int g = 0; g < 4; ++g) {
#pragma unroll
      for (int j = 0; j < 4; ++j) {
        int r = rw + rb * 32 + g * 8 + j;
        int reg = g * 4 + j;
        int sv = sa[r];
        float s = xs[r];
        float* orow = out + (size_t)r * 4096 + colb;
        orow[0]  = (float)(acc[rb][0][reg] - 8 * (sv + sw0)) * (s * wv0);
        orow[32] = (float)(acc[rb][1][reg] - 8 * (sv + sw1)) * (s * wv1);
      }
    }
  }
}

extern "C" void kernel_launch(void* const* d_in, const int* in_sizes, int n_in,
                              void* d_out, int out_size, void* d_ws, size_t ws_size,
                              hipStream_t stream) {
  const float* x = (const float*)d_in[0];
  const int* wp = (const int*)d_in[1];
  const float* wsc = (const float*)d_in[2];
  float* out = (float*)d_out;
  char* ws = (char*)d_ws;

  char* xq = ws;                                   // packed 8192*2048 = 16777216 B
  char* wq = ws + 16777216;                        // packed 4096*2048 =  8388608 B
  float* xs = (float*)(ws + 25165824);             // 8192*4
  int* sa = (int*)(ws + 25165824 + 32768);         // 8192*4
  int* sw = (int*)(ws + 25165824 + 65536);         // 4096*4

  hipLaunchKernelGGL(unpack_w, dim3(64, 16), dim3(256), 0, stream, wp, wq);
  hipLaunchKernelGGL(sum_w, dim3(4096), dim3(256), 0, stream, wp, sw);
  hipLaunchKernelGGL(quant_x, dim3(2048), dim3(256), 0, stream, x, xq, xs, sa);
  hipLaunchKernelGGL(gemm_i8, dim3(512), dim3(512), 0, stream, xq, wq, xs, sa, sw, wsc, out);
}

// Round 11
// 1108.287 us; speedup vs baseline: 2.5137x; 2.5137x over previous
//
#include <hip/hip_runtime.h>

#define SCALE_EPS 1e-5f

typedef int v4i __attribute__((ext_vector_type(4)));
typedef int v16i __attribute__((ext_vector_type(16)));

static __device__ __forceinline__ void gll16(const void* g, void* l) {
  __builtin_amdgcn_global_load_lds(
      (const __attribute__((address_space(1))) unsigned int*)g,
      (__attribute__((address_space(3))) unsigned int*)l,
      16, 0, 0);
}

// Nibble-pair packed operand format (both A and B), biased u = q+8:
//   packed byte e of a 32x32 k-pair fragment: u[k] | u[k+32]<<4
//   fragment lane l = kh*32 + (row_or_col % 32); ds_read_b128 yields BOTH
//   ks=0 (lo nibbles) and ks=1 (hi nibbles) v4i MFMA operands.
// A tile (128 rows x 64 k, packed 4 KiB): xq + (mt*64+kc)*4096,
//   off = rb*1024 + lane*16   (rb = row%128/32)
// B tile (128 cols x 64 k, packed 4 KiB): wq + (nt*64+kc)*4096,
//   off = cf*1024 + lane*16   (cf = col%128/32)
// Bias removal: C = raw - 8*(sa_signed[t] + swU_biased[o])  (exact).

// ---------------------------------------------------------------------------
// Weight unpack: packed int32 [4096][2048] -> biased nibble-pair 128-col tiles.
// ---------------------------------------------------------------------------
__global__ __launch_bounds__(256) void unpack_w(const int* __restrict__ wp,
                                                char* __restrict__ wq) {
  const int kc = blockIdx.x;   // 0..63
  const int nt = blockIdx.y;   // 0..31 (128-col tiles)
  const int tid = threadIdx.x;
  char* tile = wq + ((size_t)nt * 64 + kc) * 4096;
#pragma unroll
  for (int it = 0; it < 4; ++it) {
    int idx = it * 256 + tid;      // 0..1023
    int c = idx >> 3;              // col in tile 0..127
    int rem = idx & 7;
    int kh = rem >> 2, q = rem & 3;
    const int* src = wp + (size_t)(nt * 128 + c) * 2048 + kc * 32 + kh * 8 + q * 2;
    int i0 = src[0], i1 = src[1], j0 = src[16], j1 = src[17];
    unsigned dw = ((unsigned)i0 & 15) | (((unsigned)j0 & 15) << 4) |
                  ((((unsigned)i0 >> 4) & 15) << 8) | ((((unsigned)j0 >> 4) & 15) << 12) |
                  (((unsigned)i1 & 15) << 16) | (((unsigned)j1 & 15) << 20) |
                  ((((unsigned)i1 >> 4) & 15) << 24) | ((((unsigned)j1 >> 4) & 15) << 28);
    dw ^= 0x88888888u;  // raw nibble v -> v^8 = q+8 (biased)
    *(unsigned*)(tile + (c >> 5) * 1024 + (kh * 32 + (c & 31)) * 16 + q * 4) = dw;
  }
}

// ---------------------------------------------------------------------------
// Per-out-feature BIASED nibble sum: swU[o] = sum_k (q_w + 8).
// ---------------------------------------------------------------------------
__global__ __launch_bounds__(256) void sum_w(const int* __restrict__ wp,
                                             int* __restrict__ sw) {
  __shared__ int ls[4];
  const int row = blockIdx.x;
  const int tid = threadIdx.x;
  const v4i* src = (const v4i*)(wp + (size_t)row * 2048 + tid * 8);
  v4i m0 = src[0], m1 = src[1];
  int s = 0;
#pragma unroll
  for (int j = 0; j < 4; ++j) {
    int a = (j == 0) ? m0.x : (j == 1) ? m0.y : (j == 2) ? m0.z : m0.w;
    int b = (j == 0) ? m1.x : (j == 1) ? m1.y : (j == 2) ? m1.z : m1.w;
    s += ((a & 15) ^ 8) + (((a >> 4) & 15) ^ 8) + ((b & 15) ^ 8) + (((b >> 4) & 15) ^ 8);
  }
#pragma unroll
  for (int d = 1; d < 64; d <<= 1) s += __shfl_xor(s, d, 64);
  if ((tid & 63) == 0) ls[tid >> 6] = s;
  __syncthreads();
  if (tid == 0) sw[row] = ls[0] + ls[1] + ls[2] + ls[3];
}

// ---------------------------------------------------------------------------
// Activation quant: per-row absmax scale, q = clip(rint(x/scale),-8,7),
// nibble-pair packed 128-row tiles (u = q+8) + per-token SIGNED sum sa[t].
// ---------------------------------------------------------------------------
__global__ __launch_bounds__(256) void quant_x(const float* __restrict__ x,
                                               char* __restrict__ xq,
                                               float* __restrict__ xs,
                                               int* __restrict__ sa) {
  __shared__ float lmax[4][4];
  __shared__ int lsum[4][4];
  const int tid = threadIdx.x;
  const int w = tid >> 6;        // wave -> 16 kc chunk
  const int l = tid & 63;
  const int t0 = blockIdx.x * 4;
  const int row = l >> 4;
  const int t = t0 + row;
  const int sub = l & 15;
  const int kcl = sub >> 3;      // which of 2 kc per s
  const int kh = (sub >> 2) & 1;
  const int j = sub & 3;

  float4 va[8], vb[8];
  float m = 0.0f;
#pragma unroll
  for (int s = 0; s < 8; ++s) {
    int kc = w * 16 + s * 2 + kcl;
    const float* p = x + (size_t)t * 4096 + kc * 64 + kh * 16 + j * 4;
    va[s] = *(const float4*)(p);
    vb[s] = *(const float4*)(p + 32);
    m = fmaxf(m, fmaxf(fmaxf(fabsf(va[s].x), fabsf(va[s].y)),
                       fmaxf(fabsf(va[s].z), fabsf(va[s].w))));
    m = fmaxf(m, fmaxf(fmaxf(fabsf(vb[s].x), fabsf(vb[s].y)),
                       fmaxf(fabsf(vb[s].z), fabsf(vb[s].w))));
  }
#pragma unroll
  for (int d = 1; d < 16; d <<= 1) m = fmaxf(m, __shfl_xor(m, d, 64));
  if (sub == 0) lmax[w][row] = m;
  __syncthreads();
  float rm = fmaxf(fmaxf(lmax[0][row], lmax[1][row]),
                   fmaxf(lmax[2][row], lmax[3][row]));
  float scale = fmaxf(rm / 7.0f, SCALE_EPS);
  if (w == 0 && sub == 0) xs[t] = scale;

  // A tile: (t>>7)*64 tiles of 4 KiB; rb = (t%128)/32
  char* dst0 = xq + (size_t)(t >> 7) * 262144 + ((t & 127) >> 5) * 1024 +
               (kh * 32 + (t & 31)) * 16 + j * 4;

  int isum = 0;
#pragma unroll
  for (int s = 0; s < 8; ++s) {
    int kc = w * 16 + s * 2 + kcl;
    int q0 = (int)fminf(fmaxf(rintf(va[s].x / scale), -8.0f), 7.0f);
    int q1 = (int)fminf(fmaxf(rintf(va[s].y / scale), -8.0f), 7.0f);
    int q2 = (int)fminf(fmaxf(rintf(va[s].z / scale), -8.0f), 7.0f);
    int q3 = (int)fminf(fmaxf(rintf(va[s].w / scale), -8.0f), 7.0f);
    int q4 = (int)fminf(fmaxf(rintf(vb[s].x / scale), -8.0f), 7.0f);
    int q5 = (int)fminf(fmaxf(rintf(vb[s].y / scale), -8.0f), 7.0f);
    int q6 = (int)fminf(fmaxf(rintf(vb[s].z / scale), -8.0f), 7.0f);
    int q7 = (int)fminf(fmaxf(rintf(vb[s].w / scale), -8.0f), 7.0f);
    isum += q0 + q1 + q2 + q3 + q4 + q5 + q6 + q7;
    unsigned dw = (unsigned)((q0 + 8) | ((q4 + 8) << 4)) |
                  ((unsigned)((q1 + 8) | ((q5 + 8) << 4)) << 8) |
                  ((unsigned)((q2 + 8) | ((q6 + 8) << 4)) << 16) |
                  ((unsigned)((q3 + 8) | ((q7 + 8) << 4)) << 24);
    *(unsigned*)(dst0 + (size_t)kc * 4096) = dw;
  }
#pragma unroll
  for (int dd = 1; dd < 16; dd <<= 1) isum += __shfl_xor(isum, dd, 64);
  if (sub == 0) lsum[w][row] = isum;
  __syncthreads();
  if (w == 0 && sub == 0)
    sa[t] = lsum[0][row] + lsum[1][row] + lsum[2][row] + lsum[3][row];
}

// ---------------------------------------------------------------------------
// Packed-nibble GEMM, 128x128 tile, 4 waves (2Mx2N), BK=64, mfma 32x32x32 i8.
// R10: occupancy restructure — 3 independent 256-thread blocks per CU
// (launch_bounds(256,3); LDS ring-4 x 8K = 32K/block). Blocks have
// decorrelated barriers, so on each SIMD one wave's MFMA cluster covers
// another's unpack VALU (R8 showed MfmaUtil+VALUBusy = 100.3% -> fully
// serialized pipes in the barrier-locked 1-block config).
// Keeps R8's proven TILE skeleton: mid-tile counted vmcnt(2)+barrier,
// 4-packed-pair register rotation, splat-vector unpack, setprio, NO
// sched_barrier pinning (R9's SB(0) pinning spilled acc -> 8 GB scratch).
// Epilogue: C = raw - 8*(sa + swU)  (exact).
// ---------------------------------------------------------------------------
__global__ __launch_bounds__(256, 3) void gemm_i8(const char* __restrict__ xq,
                                                  const char* __restrict__ wq,
                                                  const float* __restrict__ xs,
                                                  const int* __restrict__ sa,
                                                  const int* __restrict__ sw,
                                                  const float* __restrict__ wsc,
                                                  float* __restrict__ out) {
  __shared__ char lds[4][8192];    // A packed 4K @0, B packed 4K @4096
  const int tid = threadIdx.x;
  const int wid = tid >> 6;        // 0..3
  const int lane = tid & 63;
  const int wm = wid >> 1;         // 0..1 : M half (64 rows)
  const int wn = wid & 1;          // 0..1 : N half (64 cols)

  // XCD-aware bijective swizzle (nwg = 2048 = 8*256)
  const int bid = blockIdx.x;
  const int wg = (bid & 7) * 256 + (bid >> 3);
  const int by = wg >> 5;          // 0..63 (M tiles of 128)
  const int bx = wg & 31;          // 0..31 (N tiles of 128)

  const int toff = tid * 16;       // 0..4095
  const char* aSrc = xq + (size_t)by * 262144;
  const char* bSrc = wq + (size_t)bx * 262144;
  const int laoff = lane * 16;

  v16i acc[2][2] = {};             // acc[rb][nf]
  v4i pA0, pA1, pB0, pB1;          // packed next-tile
  v4i a00, a01, a10, a11;          // unpacked A [rb][ks]
  v4i b00, b01, b10, b11;          // unpacked B [nf][ks]
  const v4i M4 = (v4i)(0x0f0f0f0f);

#define STAGE2(kt)                                             \
  do {                                                         \
    char* d_ = lds[(kt) & 3] + toff;                           \
    gll16(aSrc + (size_t)(kt) * 4096 + toff, d_);              \
    gll16(bSrc + (size_t)(kt) * 4096 + toff, d_ + 4096);       \
  } while (0)

  // 4 mfma: rows {rb0,rb1} x cols {nf0,nf1} for one k-slice
#define CL(xx, yy, bA, bB)                                                     \
  do {                                                                         \
    __builtin_amdgcn_s_setprio(1);                                             \
    acc[0][0] = __builtin_amdgcn_mfma_i32_32x32x32_i8(xx, bA, acc[0][0], 0, 0, 0);   \
    acc[0][1] = __builtin_amdgcn_mfma_i32_32x32x32_i8(xx, bB, acc[0][1], 0, 0, 0);   \
    acc[1][0] = __builtin_amdgcn_mfma_i32_32x32x32_i8(yy, bA, acc[1][0], 0, 0, 0);   \
    acc[1][1] = __builtin_amdgcn_mfma_i32_32x32x32_i8(yy, bB, acc[1][1], 0, 0, 0);   \
    __builtin_amdgcn_s_setprio(0);                                             \
  } while (0)

#define TILE(kt, do_stage, do_next, vm)                                      \
  do {                                                                       \
    const char* An_ = lds[((kt) + 1) & 3] + wm * 2048 + laoff;               \
    const char* Bn_ = lds[((kt) + 1) & 3] + 4096 + wn * 2048 + laoff;        \
    /* first half: ks0 MFMAs (operands unpacked at end of prev tile) */     \
    CL(a00, a10, b00, b10);                                                  \
    /* mid-tile: certify slot kt+1 (counted), sync */                        \
    if ((vm) == 2) asm volatile("s_waitcnt vmcnt(2)" ::: "memory");          \
    else if ((vm) == 0) asm volatile("s_waitcnt vmcnt(0)" ::: "memory");     \
    __builtin_amdgcn_s_barrier();                                            \
    __builtin_amdgcn_sched_barrier(0);                                       \
    /* second half: stage kt+3; read kt+1 packed; ks1 MFMAs; unpack next */  \
    if (do_stage) STAGE2((kt) + 3);                                          \
    if (do_next) {                                                           \
      pA0 = *(const v4i*)(An_);                                              \
      pA1 = *(const v4i*)(An_ + 1024);                                       \
      pB0 = *(const v4i*)(Bn_);                                              \
      pB1 = *(const v4i*)(Bn_ + 1024);                                       \
    }                                                                        \
    CL(a01, a11, b01, b11);                                                  \
    if (do_next) {                                                           \
      a00 = pA0 & M4; a01 = (pA0 >> 4) & M4;                                 \
      a10 = pA1 & M4; a11 = (pA1 >> 4) & M4;                                 \
      b00 = pB0 & M4; b01 = (pB0 >> 4) & M4;                                 \
      b10 = pB1 & M4; b11 = (pB1 >> 4) & M4;                                 \
    }                                                                        \
  } while (0)

  // prologue: stage tiles 0,1,2; certify slot 0; read+unpack slot-0 operands
  STAGE2(0); STAGE2(1); STAGE2(2);
  asm volatile("s_waitcnt vmcnt(4)" ::: "memory");
  __builtin_amdgcn_s_barrier();
  __builtin_amdgcn_sched_barrier(0);
  {
    const char* A0_ = lds[0] + wm * 2048 + laoff;
    const char* B0_ = lds[0] + 4096 + wn * 2048 + laoff;
    pA0 = *(const v4i*)(A0_);
    pA1 = *(const v4i*)(A0_ + 1024);
    pB0 = *(const v4i*)(B0_);
    pB1 = *(const v4i*)(B0_ + 1024);
    a00 = pA0 & M4; a01 = (pA0 >> 4) & M4;
    a10 = pA1 & M4; a11 = (pA1 >> 4) & M4;
    b00 = pB0 & M4; b01 = (pB0 >> 4) & M4;
    b10 = pB1 & M4; b11 = (pB1 >> 4) & M4;
  }

  for (int kt = 0; kt < 61; ++kt) TILE(kt, 1, 1, 2);  // tile 60 stages slot 63
  TILE(61, 0, 1, 2);
  TILE(62, 0, 1, 0);
  TILE(63, 0, 0, -1);

#undef TILE
#undef CL
#undef STAGE2

  // epilogue: C/D 32x32: col = lane&31, row = (reg&3)+8*(reg>>2)+4*(lane>>5)
  const int colb = bx * 128 + wn * 64 + (lane & 31);
  int sw0 = sw[colb];
  int sw1 = sw[colb + 32];
  float wv0 = wsc[colb];
  float wv1 = wsc[colb + 32];
  const int rw = by * 128 + wm * 64 + ((lane >> 5) << 2);
#pragma unroll
  for (int rb = 0; rb < 2; ++rb) {
#pragma unroll
    for (int g = 0; g < 4; ++g) {
#pragma unroll
      for (int j = 0; j < 4; ++j) {
        int r = rw + rb * 32 + g * 8 + j;
        int reg = g * 4 + j;
        int sv = sa[r];
        float s = xs[r];
        float* orow = out + (size_t)r * 4096 + colb;
        orow[0]  = (float)(acc[rb][0][reg] - 8 * (sv + sw0)) * (s * wv0);
        orow[32] = (float)(acc[rb][1][reg] - 8 * (sv + sw1)) * (s * wv1);
      }
    }
  }
}

extern "C" void kernel_launch(void* const* d_in, const int* in_sizes, int n_in,
                              void* d_out, int out_size, void* d_ws, size_t ws_size,
                              hipStream_t stream) {
  const float* x = (const float*)d_in[0];
  const int* wp = (const int*)d_in[1];
  const float* wsc = (const float*)d_in[2];
  float* out = (float*)d_out;
  char* ws = (char*)d_ws;

  char* xq = ws;                                   // packed 8192*2048 = 16777216 B
  char* wq = ws + 16777216;                        // packed 4096*2048 =  8388608 B
  float* xs = (float*)(ws + 25165824);             // 8192*4
  int* sa = (int*)(ws + 25165824 + 32768);         // 8192*4
  int* sw = (int*)(ws + 25165824 + 65536);         // 4096*4

  hipLaunchKernelGGL(unpack_w, dim3(64, 32), dim3(256), 0, stream, wp, wq);
  hipLaunchKernelGGL(sum_w, dim3(4096), dim3(256), 0, stream, wp, sw);
  hipLaunchKernelGGL(quant_x, dim3(2048), dim3(256), 0, stream, x, xq, xs, sa);
  hipLaunchKernelGGL(gemm_i8, dim3(2048), dim3(256), 0, stream, xq, wq, xs, sa, sw, wsc, out);
}

// Round 12
// 203.552 us; speedup vs baseline: 13.6862x; 5.4447x over previous
//
#include <hip/hip_runtime.h>

#define SCALE_EPS 1e-5f

typedef int v4i __attribute__((ext_vector_type(4)));
typedef int v16i __attribute__((ext_vector_type(16)));

static __device__ __forceinline__ void gll16(const void* g, void* l) {
  __builtin_amdgcn_global_load_lds(
      (const __attribute__((address_space(1))) unsigned int*)g,
      (__attribute__((address_space(3))) unsigned int*)l,
      16, 0, 0);
}

// Nibble-pair packed operand format (both A and B), biased u = q+8:
//   packed byte e of a 32x32 k-pair fragment: u[k] | u[k+32]<<4
//   fragment lane l = kh*32 + (row_or_col % 32); ds_read_b128 yields BOTH
//   ks=0 (lo nibbles) and ks=1 (hi nibbles) v4i MFMA operands.
// A tile (128 rows x 64 k, packed 4 KiB): xq + (mt*64+kc)*4096,
//   off = rb*1024 + lane*16   (rb = row%128/32)
// B tile (128 cols x 64 k, packed 4 KiB): wq + (nt*64+kc)*4096,
//   off = cf*1024 + lane*16   (cf = col%128/32)
// Bias removal: C = raw - 8*(sa_signed[t] + swU_biased[o])  (exact).

// ---------------------------------------------------------------------------
// Weight unpack: packed int32 [4096][2048] -> biased nibble-pair 128-col tiles.
// ---------------------------------------------------------------------------
__global__ __launch_bounds__(256) void unpack_w(const int* __restrict__ wp,
                                                char* __restrict__ wq) {
  const int kc = blockIdx.x;   // 0..63
  const int nt = blockIdx.y;   // 0..31 (128-col tiles)
  const int tid = threadIdx.x;
  char* tile = wq + ((size_t)nt * 64 + kc) * 4096;
#pragma unroll
  for (int it = 0; it < 4; ++it) {
    int idx = it * 256 + tid;      // 0..1023
    int c = idx >> 3;              // col in tile 0..127
    int rem = idx & 7;
    int kh = rem >> 2, q = rem & 3;
    const int* src = wp + (size_t)(nt * 128 + c) * 2048 + kc * 32 + kh * 8 + q * 2;
    int i0 = src[0], i1 = src[1], j0 = src[16], j1 = src[17];
    unsigned dw = ((unsigned)i0 & 15) | (((unsigned)j0 & 15) << 4) |
                  ((((unsigned)i0 >> 4) & 15) << 8) | ((((unsigned)j0 >> 4) & 15) << 12) |
                  (((unsigned)i1 & 15) << 16) | (((unsigned)j1 & 15) << 20) |
                  ((((unsigned)i1 >> 4) & 15) << 24) | ((((unsigned)j1 >> 4) & 15) << 28);
    dw ^= 0x88888888u;  // raw nibble v -> v^8 = q+8 (biased)
    *(unsigned*)(tile + (c >> 5) * 1024 + (kh * 32 + (c & 31)) * 16 + q * 4) = dw;
  }
}

// ---------------------------------------------------------------------------
// Per-out-feature BIASED nibble sum: swU[o] = sum_k (q_w + 8).
// ---------------------------------------------------------------------------
__global__ __launch_bounds__(256) void sum_w(const int* __restrict__ wp,
                                             int* __restrict__ sw) {
  __shared__ int ls[4];
  const int row = blockIdx.x;
  const int tid = threadIdx.x;
  const v4i* src = (const v4i*)(wp + (size_t)row * 2048 + tid * 8);
  v4i m0 = src[0], m1 = src[1];
  int s = 0;
#pragma unroll
  for (int j = 0; j < 4; ++j) {
    int a = (j == 0) ? m0.x : (j == 1) ? m0.y : (j == 2) ? m0.z : m0.w;
    int b = (j == 0) ? m1.x : (j == 1) ? m1.y : (j == 2) ? m1.z : m1.w;
    s += ((a & 15) ^ 8) + (((a >> 4) & 15) ^ 8) + ((b & 15) ^ 8) + (((b >> 4) & 15) ^ 8);
  }
#pragma unroll
  for (int d = 1; d < 64; d <<= 1) s += __shfl_xor(s, d, 64);
  if ((tid & 63) == 0) ls[tid >> 6] = s;
  __syncthreads();
  if (tid == 0) sw[row] = ls[0] + ls[1] + ls[2] + ls[3];
}

// ---------------------------------------------------------------------------
// Activation quant: per-row absmax scale, q = clip(rint(x/scale),-8,7),
// nibble-pair packed 128-row tiles (u = q+8) + per-token SIGNED sum sa[t].
// ---------------------------------------------------------------------------
__global__ __launch_bounds__(256) void quant_x(const float* __restrict__ x,
                                               char* __restrict__ xq,
                                               float* __restrict__ xs,
                                               int* __restrict__ sa) {
  __shared__ float lmax[4][4];
  __shared__ int lsum[4][4];
  const int tid = threadIdx.x;
  const int w = tid >> 6;        // wave -> 16 kc chunk
  const int l = tid & 63;
  const int t0 = blockIdx.x * 4;
  const int row = l >> 4;
  const int t = t0 + row;
  const int sub = l & 15;
  const int kcl = sub >> 3;      // which of 2 kc per s
  const int kh = (sub >> 2) & 1;
  const int j = sub & 3;

  float4 va[8], vb[8];
  float m = 0.0f;
#pragma unroll
  for (int s = 0; s < 8; ++s) {
    int kc = w * 16 + s * 2 + kcl;
    const float* p = x + (size_t)t * 4096 + kc * 64 + kh * 16 + j * 4;
    va[s] = *(const float4*)(p);
    vb[s] = *(const float4*)(p + 32);
    m = fmaxf(m, fmaxf(fmaxf(fabsf(va[s].x), fabsf(va[s].y)),
                       fmaxf(fabsf(va[s].z), fabsf(va[s].w))));
    m = fmaxf(m, fmaxf(fmaxf(fabsf(vb[s].x), fabsf(vb[s].y)),
                       fmaxf(fabsf(vb[s].z), fabsf(vb[s].w))));
  }
#pragma unroll
  for (int d = 1; d < 16; d <<= 1) m = fmaxf(m, __shfl_xor(m, d, 64));
  if (sub == 0) lmax[w][row] = m;
  __syncthreads();
  float rm = fmaxf(fmaxf(lmax[0][row], lmax[1][row]),
                   fmaxf(lmax[2][row], lmax[3][row]));
  float scale = fmaxf(rm / 7.0f, SCALE_EPS);
  if (w == 0 && sub == 0) xs[t] = scale;

  // A tile: (t>>7)*64 tiles of 4 KiB; rb = (t%128)/32
  char* dst0 = xq + (size_t)(t >> 7) * 262144 + ((t & 127) >> 5) * 1024 +
               (kh * 32 + (t & 31)) * 16 + j * 4;

  int isum = 0;
#pragma unroll
  for (int s = 0; s < 8; ++s) {
    int kc = w * 16 + s * 2 + kcl;
    int q0 = (int)fminf(fmaxf(rintf(va[s].x / scale), -8.0f), 7.0f);
    int q1 = (int)fminf(fmaxf(rintf(va[s].y / scale), -8.0f), 7.0f);
    int q2 = (int)fminf(fmaxf(rintf(va[s].z / scale), -8.0f), 7.0f);
    int q3 = (int)fminf(fmaxf(rintf(va[s].w / scale), -8.0f), 7.0f);
    int q4 = (int)fminf(fmaxf(rintf(vb[s].x / scale), -8.0f), 7.0f);
    int q5 = (int)fminf(fmaxf(rintf(vb[s].y / scale), -8.0f), 7.0f);
    int q6 = (int)fminf(fmaxf(rintf(vb[s].z / scale), -8.0f), 7.0f);
    int q7 = (int)fminf(fmaxf(rintf(vb[s].w / scale), -8.0f), 7.0f);
    isum += q0 + q1 + q2 + q3 + q4 + q5 + q6 + q7;
    unsigned dw = (unsigned)((q0 + 8) | ((q4 + 8) << 4)) |
                  ((unsigned)((q1 + 8) | ((q5 + 8) << 4)) << 8) |
                  ((unsigned)((q2 + 8) | ((q6 + 8) << 4)) << 16) |
                  ((unsigned)((q3 + 8) | ((q7 + 8) << 4)) << 24);
    *(unsigned*)(dst0 + (size_t)kc * 4096) = dw;
  }
#pragma unroll
  for (int dd = 1; dd < 16; dd <<= 1) isum += __shfl_xor(isum, dd, 64);
  if (sub == 0) lsum[w][row] = isum;
  __syncthreads();
  if (w == 0 && sub == 0)
    sa[t] = lsum[0][row] + lsum[1][row] + lsum[2][row] + lsum[3][row];
}

// ---------------------------------------------------------------------------
// Packed-nibble GEMM, 128x128 tile, 4 waves (2Mx2N), BK=64, mfma 32x32x32 i8.
// R11: (a) __launch_bounds__(256, 2) — R10's (256,3) forced the unified
// VGPR+AGPR budget to ~170 and the allocator spilled acc around the per-tile
// barrier (WRITE_SIZE 4.15 GB of scratch). Bound 2 gives slack; natural
// alloc ~150 regs still yields 3 waves/SIMD = 3 decorrelated blocks/CU.
// (b) panel-blocked XCD swizzle: per XCD, 4 panels of 8by x 8bx; panel
// working set = 8 A-strips + 8 B-strips = 4 MB = one XCD L2 (R10's flat
// swizzle had 16 MB revisit distance -> FETCH 613 MB).
// Keeps R8's proven TILE skeleton: mid-tile counted vmcnt(2)+barrier,
// packed-pair register rotation, splat-vector unpack, setprio.
// Epilogue: C = raw - 8*(sa + swU)  (exact).
// ---------------------------------------------------------------------------
__global__ __launch_bounds__(256, 2) void gemm_i8(const char* __restrict__ xq,
                                                  const char* __restrict__ wq,
                                                  const float* __restrict__ xs,
                                                  const int* __restrict__ sa,
                                                  const int* __restrict__ sw,
                                                  const float* __restrict__ wsc,
                                                  float* __restrict__ out) {
  __shared__ char lds[4][8192];    // A packed 4K @0, B packed 4K @4096
  const int tid = threadIdx.x;
  const int wid = tid >> 6;        // 0..3
  const int lane = tid & 63;
  const int wm = wid >> 1;         // 0..1 : M half (64 rows)
  const int wn = wid & 1;          // 0..1 : N half (64 cols)

  // Panel-blocked XCD swizzle (nwg = 2048 = 8 xcd x 4 panels x 8by x 8bx):
  // per XCD, walk 4 panels of (8 by x 8 bx); panel = 4 MB = one XCD L2.
  const int bid = blockIdx.x;
  const int xcd = bid & 7;
  const int i = bid >> 3;          // 0..255 within XCD
  const int p = i >> 6;            // panel 0..3
  const int jj = i & 63;
  const int by = xcd * 8 + (jj >> 3);   // 0..63 (M tiles of 128)
  const int bx = p * 8 + (jj & 7);      // 0..31 (N tiles of 128)

  const int toff = tid * 16;       // 0..4095
  const char* aSrc = xq + (size_t)by * 262144;
  const char* bSrc = wq + (size_t)bx * 262144;
  const int laoff = lane * 16;

  v16i acc[2][2] = {};             // acc[rb][nf]
  v4i pA0, pA1, pB0, pB1;          // packed next-tile
  v4i a00, a01, a10, a11;          // unpacked A [rb][ks]
  v4i b00, b01, b10, b11;          // unpacked B [nf][ks]
  const v4i M4 = (v4i)(0x0f0f0f0f);

#define STAGE2(kt)                                             \
  do {                                                         \
    char* d_ = lds[(kt) & 3] + toff;                           \
    gll16(aSrc + (size_t)(kt) * 4096 + toff, d_);              \
    gll16(bSrc + (size_t)(kt) * 4096 + toff, d_ + 4096);       \
  } while (0)

  // 4 mfma: rows {rb0,rb1} x cols {nf0,nf1} for one k-slice
#define CL(xx, yy, bA, bB)                                                     \
  do {                                                                         \
    __builtin_amdgcn_s_setprio(1);                                             \
    acc[0][0] = __builtin_amdgcn_mfma_i32_32x32x32_i8(xx, bA, acc[0][0], 0, 0, 0);   \
    acc[0][1] = __builtin_amdgcn_mfma_i32_32x32x32_i8(xx, bB, acc[0][1], 0, 0, 0);   \
    acc[1][0] = __builtin_amdgcn_mfma_i32_32x32x32_i8(yy, bA, acc[1][0], 0, 0, 0);   \
    acc[1][1] = __builtin_amdgcn_mfma_i32_32x32x32_i8(yy, bB, acc[1][1], 0, 0, 0);   \
    __builtin_amdgcn_s_setprio(0);                                             \
  } while (0)

#define TILE(kt, do_stage, do_next, vm)                                      \
  do {                                                                       \
    const char* An_ = lds[((kt) + 1) & 3] + wm * 2048 + laoff;               \
    const char* Bn_ = lds[((kt) + 1) & 3] + 4096 + wn * 2048 + laoff;        \
    /* first half: ks0 MFMAs (operands unpacked at end of prev tile) */     \
    CL(a00, a10, b00, b10);                                                  \
    /* mid-tile: certify slot kt+1 (counted), sync */                        \
    if ((vm) == 2) asm volatile("s_waitcnt vmcnt(2)" ::: "memory");          \
    else if ((vm) == 0) asm volatile("s_waitcnt vmcnt(0)" ::: "memory");     \
    __builtin_amdgcn_s_barrier();                                            \
    __builtin_amdgcn_sched_barrier(0);                                       \
    /* second half: stage kt+3; read kt+1 packed; ks1 MFMAs; unpack next */  \
    if (do_stage) STAGE2((kt) + 3);                                          \
    if (do_next) {                                                           \
      pA0 = *(const v4i*)(An_);                                              \
      pA1 = *(const v4i*)(An_ + 1024);                                       \
      pB0 = *(const v4i*)(Bn_);                                              \
      pB1 = *(const v4i*)(Bn_ + 1024);                                       \
    }                                                                        \
    CL(a01, a11, b01, b11);                                                  \
    if (do_next) {                                                           \
      a00 = pA0 & M4; a01 = (pA0 >> 4) & M4;                                 \
      a10 = pA1 & M4; a11 = (pA1 >> 4) & M4;                                 \
      b00 = pB0 & M4; b01 = (pB0 >> 4) & M4;                                 \
      b10 = pB1 & M4; b11 = (pB1 >> 4) & M4;                                 \
    }                                                                        \
  } while (0)

  // prologue: stage tiles 0,1,2; certify slot 0; read+unpack slot-0 operands
  STAGE2(0); STAGE2(1); STAGE2(2);
  asm volatile("s_waitcnt vmcnt(4)" ::: "memory");
  __builtin_amdgcn_s_barrier();
  __builtin_amdgcn_sched_barrier(0);
  {
    const char* A0_ = lds[0] + wm * 2048 + laoff;
    const char* B0_ = lds[0] + 4096 + wn * 2048 + laoff;
    pA0 = *(const v4i*)(A0_);
    pA1 = *(const v4i*)(A0_ + 1024);
    pB0 = *(const v4i*)(B0_);
    pB1 = *(const v4i*)(B0_ + 1024);
    a00 = pA0 & M4; a01 = (pA0 >> 4) & M4;
    a10 = pA1 & M4; a11 = (pA1 >> 4) & M4;
    b00 = pB0 & M4; b01 = (pB0 >> 4) & M4;
    b10 = pB1 & M4; b11 = (pB1 >> 4) & M4;
  }

  for (int kt = 0; kt < 61; ++kt) TILE(kt, 1, 1, 2);  // tile 60 stages slot 63
  TILE(61, 0, 1, 2);
  TILE(62, 0, 1, 0);
  TILE(63, 0, 0, -1);

#undef TILE
#undef CL
#undef STAGE2

  // epilogue: C/D 32x32: col = lane&31, row = (reg&3)+8*(reg>>2)+4*(lane>>5)
  const int colb = bx * 128 + wn * 64 + (lane & 31);
  int sw0 = sw[colb];
  int sw1 = sw[colb + 32];
  float wv0 = wsc[colb];
  float wv1 = wsc[colb + 32];
  const int rw = by * 128 + wm * 64 + ((lane >> 5) << 2);
#pragma unroll
  for (int rb = 0; rb < 2; ++rb) {
#pragma unroll
    for (int g = 0; g < 4; ++g) {
#pragma unroll
      for (int j = 0; j < 4; ++j) {
        int r = rw + rb * 32 + g * 8 + j;
        int reg = g * 4 + j;
        int sv = sa[r];
        float s = xs[r];
        float* orow = out + (size_t)r * 4096 + colb;
        orow[0]  = (float)(acc[rb][0][reg] - 8 * (sv + sw0)) * (s * wv0);
        orow[32] = (float)(acc[rb][1][reg] - 8 * (sv + sw1)) * (s * wv1);
      }
    }
  }
}

extern "C" void kernel_launch(void* const* d_in, const int* in_sizes, int n_in,
                              void* d_out, int out_size, void* d_ws, size_t ws_size,
                              hipStream_t stream) {
  const float* x = (const float*)d_in[0];
  const int* wp = (const int*)d_in[1];
  const float* wsc = (const float*)d_in[2];
  float* out = (float*)d_out;
  char* ws = (char*)d_ws;

  char* xq = ws;                                   // packed 8192*2048 = 16777216 B
  char* wq = ws + 16777216;                        // packed 4096*2048 =  8388608 B
  float* xs = (float*)(ws + 25165824);             // 8192*4
  int* sa = (int*)(ws + 25165824 + 32768);         // 8192*4
  int* sw = (int*)(ws + 25165824 + 65536);         // 4096*4

  hipLaunchKernelGGL(unpack_w, dim3(64, 32), dim3(256), 0, stream, wp, wq);
  hipLaunchKernelGGL(sum_w, dim3(4096), dim3(256), 0, stream, wp, sw);
  hipLaunchKernelGGL(quant_x, dim3(2048), dim3(256), 0, stream, x, xq, xs, sa);
  hipLaunchKernelGGL(gemm_i8, dim3(2048), dim3(256), 0, stream, xq, wq, xs, sa, sw, wsc, out);
}